// Round 5
// baseline (2283.043 us; speedup 1.0000x reference)
//
#include <hip/hip_runtime.h>

// SRM neuron: per-row 50-tap 'same' conv -> threshold -> refractory scan.
// B=4096 rows, T=16384.
// R5 = R4 with compile fix: native ext_vector float4 for nontemporal builtins.
//   K1: conv -> candidate bits (ballot bitmask in d_ws). Rows split into 8
//       chunks of 2048 steps per wave -> 32768 waves, 8 blocks/CU.
//   K2: wave-per-row scan over the bitmask. Empty groups (the ~always case)
//       take a SCALAR fast path: store 1KB of zeros. Transfer-map scan only
//       where candidates exist. Exact for any input.
// Fallback: validated R3 single kernel if ws_size is too small.

#define TLEN   16384
#define NROWS  4096
#define GRP    256     // elements per group (64 lanes x 4)
#define NGRP   64      // groups per row
#define CHUNK  2048    // steps per K1 wave
#define GPC    8       // groups per chunk
#define KLEN   50
#define WPB    4       // waves per 256-thread block

#define WS_WORDS ((size_t)NROWS * NGRP * 4)   // u64 words of cand bits
#define WS_NEED  (WS_WORDS * 8)               // 8,388,608 bytes

typedef float f4 __attribute__((ext_vector_type(4)));

__device__ __forceinline__ float uniformf(float x) {
    return __int_as_float(__builtin_amdgcn_readfirstlane(__float_as_int(x)));
}

// compose: r[s] = then[first[s]]  (apply `first`, then `then`)
__device__ __forceinline__ int map_compose(int first, int then) {
    int r = 0;
#pragma unroll
    for (int s = 0; s < 4; ++s) {
        int a = (first >> (2 * s)) & 3;
        int b = (then >> (2 * a)) & 3;
        r |= b << (2 * s);
    }
    return r;
}

// ---------------- K1: conv -> candidate bitmask ----------------
__global__ __launch_bounds__(256, 8)
void conv_cand_kernel(const float* __restrict__ I,
                      const float* __restrict__ p_tau_m,
                      const float* __restrict__ p_tau_s,
                      const float* __restrict__ p_v_th,
                      const float* __restrict__ p_v_reset,
                      unsigned long long* __restrict__ wsb)
{
    const int lane  = threadIdx.x & 63;
    const int wid   = threadIdx.x >> 6;
    const int w     = blockIdx.x * WPB + wid;   // 0 .. 32767
    const int row   = w >> 3;
    const int chunk = w & 7;
    const int base  = chunk * CHUNK;

    const float tau_m   = p_tau_m[0];
    const float tau_s   = p_tau_s[0];
    const float v_th    = p_v_th[0];
    const float v_reset = p_v_reset[0];

    // Taps pinned wave-uniform (SGPR file) -- arithmetic identical to the
    // R1-R3 kernels which validated absmax 0.0.
    float ku[KLEN];
    float ksum = 0.0f;
#pragma unroll
    for (int t = 0; t < KLEN; ++t) {
        float ft = (float)t;
        float v = expf(-ft / tau_m) - expf(-ft / tau_s);
        ksum += v;
        ku[t] = uniformf(v);
    }
    const float kden = uniformf(ksum + 1e-10f);
    float kt[KLEN];
#pragma unroll
    for (int t = 0; t < KLEN; ++t) kt[t] = uniformf(ku[t] / kden);

    const float* Irow = I + (size_t)row * TLEN;

    float Pv[4], Cv[4], Nv[4];
    if (chunk == 0) {
        Pv[0] = Pv[1] = Pv[2] = Pv[3] = 0.0f;   // x[t<0] = 0
    } else {
        f4 a = *(const f4*)(Irow + base - GRP + 4 * lane);
        Pv[0] = a.x; Pv[1] = a.y; Pv[2] = a.z; Pv[3] = a.w;
    }
    {
        f4 a = *(const f4*)(Irow + base + 4 * lane);
        Cv[0] = a.x; Cv[1] = a.y; Cv[2] = a.z; Cv[3] = a.w;
        f4 c = *(const f4*)(Irow + base + GRP + 4 * lane);
        Nv[0] = c.x; Nv[1] = c.y; Nv[2] = c.z; Nv[3] = c.w;
    }

    // bpermute byte-addresses for lane shifts q = -7..6
    const int addr_m7 = ((lane - 7) & 63) << 2;
    const int addr_m6 = ((lane - 6) & 63) << 2;
    const int addr_m5 = ((lane - 5) & 63) << 2;
    const int addr_m4 = ((lane - 4) & 63) << 2;
    const int addr_m3 = ((lane - 3) & 63) << 2;
    const int addr_m2 = ((lane - 2) & 63) << 2;
    const int addr_m1 = ((lane - 1) & 63) << 2;
    const int addr_p1 = ((lane + 1) & 63) << 2;
    const int addr_p2 = ((lane + 2) & 63) << 2;
    const int addr_p3 = ((lane + 3) & 63) << 2;
    const int addr_p4 = ((lane + 4) & 63) << 2;
    const int addr_p5 = ((lane + 5) & 63) << 2;
    const int addr_p6 = ((lane + 6) & 63) << 2;

    for (int g = 0; g < GPC; ++g) {
        // ---- prefetch group g+2 (real halo data past the chunk) ----
        float Lv[4];
        const int nidx = base + (g + 2) * GRP;
        if (nidx < TLEN) {
            f4 a = __builtin_nontemporal_load((const f4*)(Irow + nidx + 4 * lane));
            Lv[0] = a.x; Lv[1] = a.y; Lv[2] = a.z; Lv[3] = a.w;
        } else {
            Lv[0] = Lv[1] = Lv[2] = Lv[3] = 0.0f;
        }

        // ---- convolution (identical arithmetic to R3) ----
        float acc[4];
        acc[0] = acc[1] = acc[2] = acc[3] = 0.0f;

#pragma unroll
        for (int o = -25; o <= 27; ++o) {      // window offset rel. to 4l
            const int q = o >> 2;              // lane shift (floor)
            const int j = o & 3;               // register within set
            float w2;
            if (q == 0) {
                w2 = Cv[j];
            } else if (q < 0) {
                float src = (lane >= 64 + q) ? Pv[j] : Cv[j];
                int addr = (q == -7) ? addr_m7 : (q == -6) ? addr_m6
                         : (q == -5) ? addr_m5 : (q == -4) ? addr_m4
                         : (q == -3) ? addr_m3 : (q == -2) ? addr_m2 : addr_m1;
                w2 = __int_as_float(__builtin_amdgcn_ds_bpermute(addr, __float_as_int(src)));
            } else {
                float src = (lane < q) ? Nv[j] : Cv[j];
                int addr = (q == 1) ? addr_p1 : (q == 2) ? addr_p2
                         : (q == 3) ? addr_p3 : (q == 4) ? addr_p4
                         : (q == 5) ? addr_p5 : addr_p6;
                w2 = __int_as_float(__builtin_amdgcn_ds_bpermute(addr, __float_as_int(src)));
            }
#pragma unroll
            for (int k = 0; k < 4; ++k) {
                const int jj = k + 24 - o;
                if (jj >= 0 && jj < KLEN)
                    acc[k] = fmaf(kt[jj], w2, acc[k]);
            }
        }

        // ---- candidates (exact reference arithmetic) ----
        const int tb = base + g * GRP + 4 * lane;
        int cand[4];
#pragma unroll
        for (int k = 0; k < 4; ++k) {
            float vfree = v_reset + acc[k] / 100.0f;   // true IEEE divide
            cand[k] = (vfree >= v_th) ? 1 : 0;
        }
        cand[0] &= (tb != 0);   // spikes[0] forced 0 (loop starts at t=1)

        // ---- pack to bitmask: bit l of word k = cand_k of lane l ----
        const unsigned long long b0 = __ballot(cand[0] != 0);
        const unsigned long long b1 = __ballot(cand[1] != 0);
        const unsigned long long b2 = __ballot(cand[2] != 0);
        const unsigned long long b3 = __ballot(cand[3] != 0);
        unsigned long long v = (lane & 1) ? ((lane & 2) ? b3 : b1)
                                          : ((lane & 2) ? b2 : b0);
        if (lane < 4) {
            const size_t widx = ((size_t)row * NGRP + (size_t)(chunk * GPC + g)) * 4 + lane;
            __builtin_nontemporal_store(v, wsb + widx);
        }

        // ---- rotate register sets ----
#pragma unroll
        for (int j = 0; j < 4; ++j) { Pv[j] = Cv[j]; Cv[j] = Nv[j]; Nv[j] = Lv[j]; }
    }
}

// ---------------- K2: scan bitmask -> spikes ----------------
__global__ __launch_bounds__(256, 8)
void expand_kernel(const unsigned long long* __restrict__ wsb,
                   float* __restrict__ out)
{
    const int lane = threadIdx.x & 63;
    const int wid  = threadIdx.x >> 6;
    const int row  = blockIdx.x * WPB + wid;

    float* Orow = out + (size_t)row * TLEN;

    int r0 = 0;  // wave-uniform refractory state entering this group

    for (int g = 0; g < NGRP; ++g) {
        // Uniform-address loads -> scalar loads + scalar branch.
        const unsigned long long* pw = wsb + ((size_t)row * NGRP + g) * 4;
        const unsigned long long b0 = pw[0];
        const unsigned long long b1 = pw[1];
        const unsigned long long b2 = pw[2];
        const unsigned long long b3 = pw[3];

        f4 o0;
        if ((b0 | b1 | b2 | b3) == 0ULL) {
            // No candidate in this 256-group: spikes all zero; any refractory
            // countdown (<=3) expires within the group.
            o0 = (f4){0.0f, 0.0f, 0.0f, 0.0f};
            r0 = 0;
        } else {
            int cand[4];
            cand[0] = (int)((b0 >> lane) & 1ULL);
            cand[1] = (int)((b1 >> lane) & 1ULL);
            cand[2] = (int)((b2 >> lane) & 1ULL);
            cand[3] = (int)((b3 >> lane) & 1ULL);

            // ---- per-lane 4-step transfer map for incoming ref in {0..3} ----
            int s0 = 0, s1 = 1, s2 = 2, s3 = 3;
#pragma unroll
            for (int k = 0; k < 4; ++k) {
                const int c3 = cand[k] ? 3 : 0;
                s0 = (s0 > 0) ? (s0 - 1) : c3;
                s1 = (s1 > 0) ? (s1 - 1) : c3;
                s2 = (s2 > 0) ? (s2 - 1) : c3;
                s3 = (s3 > 0) ? (s3 - 1) : c3;
            }
            int P = s0 | (s1 << 2) | (s2 << 4) | (s3 << 6);

            // ---- inclusive prefix composition across 64 lanes ----
#pragma unroll
            for (int d = 1; d < 64; d <<= 1) {
                const int prev = __shfl_up(P, d, 64);
                const int comp = map_compose(prev, P);
                P = (lane >= d) ? comp : P;
            }
            const int Pprev = __shfl_up(P, 1, 64);
            const int sin0  = (lane == 0) ? r0 : ((Pprev >> (2 * r0)) & 3);
            const int Pfull = __shfl(P, 63, 64);
            r0 = (Pfull >> (2 * r0)) & 3;   // carry to next group

            // ---- replay with true incoming state ----
            int s = sin0;
            float sp[4];
#pragma unroll
            for (int k = 0; k < 4; ++k) {
                const int spike = (s == 0) & cand[k];
                sp[k] = spike ? 1.0f : 0.0f;
                s = (s > 0) ? (s - 1) : (cand[k] ? 3 : 0);
            }
            o0.x = sp[0]; o0.y = sp[1]; o0.z = sp[2]; o0.w = sp[3];
        }

        __builtin_nontemporal_store(o0, (f4*)(Orow + g * GRP + 4 * lane));
    }
}

// ---------------- Fallback: validated R3 single kernel ----------------
__global__ __launch_bounds__(256, 4)
void srm_kernel(const float* __restrict__ I,
                const float* __restrict__ p_tau_m,
                const float* __restrict__ p_tau_s,
                const float* __restrict__ p_v_th,
                const float* __restrict__ p_v_reset,
                float* __restrict__ out)
{
    const int lane = threadIdx.x & 63;
    const int wid  = threadIdx.x >> 6;
    const int row  = blockIdx.x * WPB + wid;

    const float tau_m   = p_tau_m[0];
    const float tau_s   = p_tau_s[0];
    const float v_th    = p_v_th[0];
    const float v_reset = p_v_reset[0];

    float ku[KLEN];
    float ksum = 0.0f;
#pragma unroll
    for (int t = 0; t < KLEN; ++t) {
        float ft = (float)t;
        float v = expf(-ft / tau_m) - expf(-ft / tau_s);
        ksum += v;
        ku[t] = uniformf(v);
    }
    const float kden = uniformf(ksum + 1e-10f);
    float kt[KLEN];
#pragma unroll
    for (int t = 0; t < KLEN; ++t) kt[t] = uniformf(ku[t] / kden);

    const float* Irow = I + (size_t)row * TLEN;
    float* Orow = out + (size_t)row * TLEN;

    float Pv[4], Cv[4], Nv[4];
#pragma unroll
    for (int j = 0; j < 4; ++j) Pv[j] = 0.0f;
    {
        f4 a = *(const f4*)(Irow + 0 * GRP + 4 * lane);
        Cv[0] = a.x; Cv[1] = a.y; Cv[2] = a.z; Cv[3] = a.w;
        f4 c = *(const f4*)(Irow + 1 * GRP + 4 * lane);
        Nv[0] = c.x; Nv[1] = c.y; Nv[2] = c.z; Nv[3] = c.w;
    }

    const int addr_m7 = ((lane - 7) & 63) << 2;
    const int addr_m6 = ((lane - 6) & 63) << 2;
    const int addr_m5 = ((lane - 5) & 63) << 2;
    const int addr_m4 = ((lane - 4) & 63) << 2;
    const int addr_m3 = ((lane - 3) & 63) << 2;
    const int addr_m2 = ((lane - 2) & 63) << 2;
    const int addr_m1 = ((lane - 1) & 63) << 2;
    const int addr_p1 = ((lane + 1) & 63) << 2;
    const int addr_p2 = ((lane + 2) & 63) << 2;
    const int addr_p3 = ((lane + 3) & 63) << 2;
    const int addr_p4 = ((lane + 4) & 63) << 2;
    const int addr_p5 = ((lane + 5) & 63) << 2;
    const int addr_p6 = ((lane + 6) & 63) << 2;

    int r0 = 0;

    for (int g = 0; g < NGRP; ++g) {
        float Lv[4];
        if (g + 2 < NGRP) {
            f4 a = *(const f4*)(Irow + (size_t)(g + 2) * GRP + 4 * lane);
            Lv[0] = a.x; Lv[1] = a.y; Lv[2] = a.z; Lv[3] = a.w;
        } else {
            Lv[0] = Lv[1] = Lv[2] = Lv[3] = 0.0f;
        }

        float acc[4];
        acc[0] = acc[1] = acc[2] = acc[3] = 0.0f;

#pragma unroll
        for (int o = -25; o <= 27; ++o) {
            const int q = o >> 2;
            const int j = o & 3;
            float w;
            if (q == 0) {
                w = Cv[j];
            } else if (q < 0) {
                float src = (lane >= 64 + q) ? Pv[j] : Cv[j];
                int addr = (q == -7) ? addr_m7 : (q == -6) ? addr_m6
                         : (q == -5) ? addr_m5 : (q == -4) ? addr_m4
                         : (q == -3) ? addr_m3 : (q == -2) ? addr_m2 : addr_m1;
                w = __int_as_float(__builtin_amdgcn_ds_bpermute(addr, __float_as_int(src)));
            } else {
                float src = (lane < q) ? Nv[j] : Cv[j];
                int addr = (q == 1) ? addr_p1 : (q == 2) ? addr_p2
                         : (q == 3) ? addr_p3 : (q == 4) ? addr_p4
                         : (q == 5) ? addr_p5 : addr_p6;
                w = __int_as_float(__builtin_amdgcn_ds_bpermute(addr, __float_as_int(src)));
            }
#pragma unroll
            for (int k = 0; k < 4; ++k) {
                const int jj = k + 24 - o;
                if (jj >= 0 && jj < KLEN)
                    acc[k] = fmaf(kt[jj], w, acc[k]);
            }
        }

        const int tb = g * GRP + 4 * lane;
        int cand[4];
#pragma unroll
        for (int k = 0; k < 4; ++k) {
            float vfree = v_reset + acc[k] / 100.0f;
            cand[k] = (vfree >= v_th) ? 1 : 0;
        }
        cand[0] &= (tb != 0);

        const int cm = cand[0] | cand[1] | cand[2] | cand[3];
        const unsigned long long anyc = __ballot(cm != 0);

        f4 o0;
        if (anyc == 0ULL) {
            o0 = (f4){0.0f, 0.0f, 0.0f, 0.0f};
            r0 = 0;
        } else {
            int s0 = 0, s1 = 1, s2 = 2, s3 = 3;
#pragma unroll
            for (int k = 0; k < 4; ++k) {
                const int c3 = cand[k] ? 3 : 0;
                s0 = (s0 > 0) ? (s0 - 1) : c3;
                s1 = (s1 > 0) ? (s1 - 1) : c3;
                s2 = (s2 > 0) ? (s2 - 1) : c3;
                s3 = (s3 > 0) ? (s3 - 1) : c3;
            }
            int P = s0 | (s1 << 2) | (s2 << 4) | (s3 << 6);
#pragma unroll
            for (int d = 1; d < 64; d <<= 1) {
                const int prev = __shfl_up(P, d, 64);
                const int comp = map_compose(prev, P);
                P = (lane >= d) ? comp : P;
            }
            const int Pprev = __shfl_up(P, 1, 64);
            const int sin0  = (lane == 0) ? r0 : ((Pprev >> (2 * r0)) & 3);
            const int Pfull = __shfl(P, 63, 64);
            r0 = (Pfull >> (2 * r0)) & 3;

            int s = sin0;
            float sp[4];
#pragma unroll
            for (int k = 0; k < 4; ++k) {
                const int spike = (s == 0) & cand[k];
                sp[k] = spike ? 1.0f : 0.0f;
                s = (s > 0) ? (s - 1) : (cand[k] ? 3 : 0);
            }
            o0.x = sp[0]; o0.y = sp[1]; o0.z = sp[2]; o0.w = sp[3];
        }

        *(f4*)(Orow + tb) = o0;

#pragma unroll
        for (int j = 0; j < 4; ++j) { Pv[j] = Cv[j]; Cv[j] = Nv[j]; Nv[j] = Lv[j]; }
    }
}

extern "C" void kernel_launch(void* const* d_in, const int* in_sizes, int n_in,
                              void* d_out, int out_size, void* d_ws, size_t ws_size,
                              hipStream_t stream) {
    const float* I       = (const float*)d_in[0];
    const float* tau_m   = (const float*)d_in[1];
    const float* tau_s   = (const float*)d_in[2];
    const float* v_th    = (const float*)d_in[3];
    const float* v_reset = (const float*)d_in[4];
    float* out = (float*)d_out;

    if (ws_size >= WS_NEED) {
        unsigned long long* wsb = (unsigned long long*)d_ws;
        conv_cand_kernel<<<dim3(NROWS * 8 / WPB), dim3(256), 0, stream>>>(
            I, tau_m, tau_s, v_th, v_reset, wsb);
        expand_kernel<<<dim3(NROWS / WPB), dim3(256), 0, stream>>>(wsb, out);
    } else {
        srm_kernel<<<dim3(NROWS / WPB), dim3(256), 0, stream>>>(
            I, tau_m, tau_s, v_th, v_reset, out);
    }
}

// Round 6
// 198.174 us; speedup vs baseline: 11.5204x; 11.5204x over previous
//
#include <hip/hip_runtime.h>

// SRM neuron: per-row 50-tap 'same' conv -> threshold -> refractory scan.
// B=4096 rows, T=16384. One wave per row, 4 timesteps/lane, 64 groups of 256.
// R6 = validated R3 single kernel with the spill fixed: __launch_bounds__(256)
//      ONLY (no min-occupancy hint). R1-R5 pinned VGPRs at 64/32 via
//      launch_bounds' second arg, forcing scratch spills that showed up as
//      1.3-6 GB of phantom HBM FETCH. Working set is ~100 VGPRs; let the
//      allocator have them (cap 512 at flat workgroup 256).

#define TLEN  16384
#define NROWS 4096
#define GRP   256     // elements per group (64 lanes x 4)
#define NGRP  64      // groups per row
#define KLEN  50
#define WPB   4       // waves (rows) per 256-thread block

typedef float f4 __attribute__((ext_vector_type(4)));

__device__ __forceinline__ float uniformf(float x) {
    return __int_as_float(__builtin_amdgcn_readfirstlane(__float_as_int(x)));
}

// compose: r[s] = then[first[s]]  (apply `first`, then `then`)
__device__ __forceinline__ int map_compose(int first, int then) {
    int r = 0;
#pragma unroll
    for (int s = 0; s < 4; ++s) {
        int a = (first >> (2 * s)) & 3;
        int b = (then >> (2 * a)) & 3;
        r |= b << (2 * s);
    }
    return r;
}

__global__ __launch_bounds__(256)
void srm_kernel(const float* __restrict__ I,
                const float* __restrict__ p_tau_m,
                const float* __restrict__ p_tau_s,
                const float* __restrict__ p_v_th,
                const float* __restrict__ p_v_reset,
                float* __restrict__ out)
{
    const int lane = threadIdx.x & 63;
    const int wid  = threadIdx.x >> 6;
    const int row  = blockIdx.x * WPB + wid;

    const float tau_m   = p_tau_m[0];
    const float tau_s   = p_tau_s[0];
    const float v_th    = p_v_th[0];
    const float v_reset = p_v_reset[0];

    // Taps pinned wave-uniform via readfirstlane -> SGPR file (50 regs off
    // the VGPR budget). Arithmetic identical to R1-R3 (validated absmax 0.0).
    float ku[KLEN];
    float ksum = 0.0f;
#pragma unroll
    for (int t = 0; t < KLEN; ++t) {
        float ft = (float)t;
        float v = expf(-ft / tau_m) - expf(-ft / tau_s);
        ksum += v;
        ku[t] = uniformf(v);
    }
    const float kden = uniformf(ksum + 1e-10f);
    float kt[KLEN];
#pragma unroll
    for (int t = 0; t < KLEN; ++t) kt[t] = uniformf(ku[t] / kden);

    const float* Irow = I + (size_t)row * TLEN;
    float* Orow = out + (size_t)row * TLEN;

    // Rotating per-group register sets (4 floats/lane per 256-elem group).
    float Pv[4], Cv[4], Nv[4];
#pragma unroll
    for (int j = 0; j < 4; ++j) Pv[j] = 0.0f;   // x[t<0] = 0

    {
        f4 a = *(const f4*)(Irow + 0 * GRP + 4 * lane);
        Cv[0] = a.x; Cv[1] = a.y; Cv[2] = a.z; Cv[3] = a.w;
        f4 c = *(const f4*)(Irow + 1 * GRP + 4 * lane);
        Nv[0] = c.x; Nv[1] = c.y; Nv[2] = c.z; Nv[3] = c.w;
    }

    // bpermute byte-addresses for lane shifts q = -7..6
    const int addr_m7 = ((lane - 7) & 63) << 2;
    const int addr_m6 = ((lane - 6) & 63) << 2;
    const int addr_m5 = ((lane - 5) & 63) << 2;
    const int addr_m4 = ((lane - 4) & 63) << 2;
    const int addr_m3 = ((lane - 3) & 63) << 2;
    const int addr_m2 = ((lane - 2) & 63) << 2;
    const int addr_m1 = ((lane - 1) & 63) << 2;
    const int addr_p1 = ((lane + 1) & 63) << 2;
    const int addr_p2 = ((lane + 2) & 63) << 2;
    const int addr_p3 = ((lane + 3) & 63) << 2;
    const int addr_p4 = ((lane + 4) & 63) << 2;
    const int addr_p5 = ((lane + 5) & 63) << 2;
    const int addr_p6 = ((lane + 6) & 63) << 2;

    int r0 = 0;  // wave-uniform refractory state entering this group

    for (int g = 0; g < NGRP; ++g) {
        // ---- prefetch group g+2 (zeros past the end), streaming load ----
        float Lv[4];
        if (g + 2 < NGRP) {
            f4 a = __builtin_nontemporal_load(
                (const f4*)(Irow + (size_t)(g + 2) * GRP + 4 * lane));
            Lv[0] = a.x; Lv[1] = a.y; Lv[2] = a.z; Lv[3] = a.w;
        } else {
            Lv[0] = Lv[1] = Lv[2] = Lv[3] = 0.0f;
        }

        // ---- convolution: out[4l+k] = sum_j kt[j] * x[g*256 + 4l + k + 24 - j] ----
        float acc[4];
        acc[0] = acc[1] = acc[2] = acc[3] = 0.0f;

#pragma unroll
        for (int o = -25; o <= 27; ++o) {      // window offset rel. to 4l
            const int q = o >> 2;              // lane shift (floor)
            const int j = o & 3;               // register within set
            float w;
            if (q == 0) {
                w = Cv[j];
            } else if (q < 0) {
                // source lanes >= 64+q supply prev-group values
                float src = (lane >= 64 + q) ? Pv[j] : Cv[j];
                int addr = (q == -7) ? addr_m7 : (q == -6) ? addr_m6
                         : (q == -5) ? addr_m5 : (q == -4) ? addr_m4
                         : (q == -3) ? addr_m3 : (q == -2) ? addr_m2 : addr_m1;
                w = __int_as_float(__builtin_amdgcn_ds_bpermute(addr, __float_as_int(src)));
            } else {
                // source lanes < q supply next-group values
                float src = (lane < q) ? Nv[j] : Cv[j];
                int addr = (q == 1) ? addr_p1 : (q == 2) ? addr_p2
                         : (q == 3) ? addr_p3 : (q == 4) ? addr_p4
                         : (q == 5) ? addr_p5 : addr_p6;
                w = __int_as_float(__builtin_amdgcn_ds_bpermute(addr, __float_as_int(src)));
            }
#pragma unroll
            for (int k = 0; k < 4; ++k) {
                const int jj = k + 24 - o;
                if (jj >= 0 && jj < KLEN)
                    acc[k] = fmaf(kt[jj], w, acc[k]);
            }
        }

        // ---- candidates (exact reference arithmetic) ----
        const int tb = g * GRP + 4 * lane;
        int cand[4];
#pragma unroll
        for (int k = 0; k < 4; ++k) {
            float vfree = v_reset + acc[k] / 100.0f;   // true IEEE divide
            cand[k] = (vfree >= v_th) ? 1 : 0;
        }
        cand[0] &= (tb != 0);   // spikes[0] forced 0 (loop starts at t=1)

        const int cm = cand[0] | cand[1] | cand[2] | cand[3];
        const unsigned long long anyc = __ballot(cm != 0);

        f4 o0;
        if (anyc == 0ULL) {
            // No crossing in this 256-group: all spikes zero; any refractory
            // countdown (<=3) expires within the group.
            o0 = (f4){0.0f, 0.0f, 0.0f, 0.0f};
            r0 = 0;
        } else {
            // ---- per-lane 4-step transfer map for incoming ref in {0..3} ----
            int s0 = 0, s1 = 1, s2 = 2, s3 = 3;
#pragma unroll
            for (int k = 0; k < 4; ++k) {
                const int c3 = cand[k] ? 3 : 0;
                s0 = (s0 > 0) ? (s0 - 1) : c3;
                s1 = (s1 > 0) ? (s1 - 1) : c3;
                s2 = (s2 > 0) ? (s2 - 1) : c3;
                s3 = (s3 > 0) ? (s3 - 1) : c3;
            }
            int P = s0 | (s1 << 2) | (s2 << 4) | (s3 << 6);

            // ---- inclusive prefix composition across 64 lanes ----
#pragma unroll
            for (int d = 1; d < 64; d <<= 1) {
                const int prev = __shfl_up(P, d, 64);
                const int comp = map_compose(prev, P);
                P = (lane >= d) ? comp : P;
            }
            const int Pprev = __shfl_up(P, 1, 64);
            const int sin0  = (lane == 0) ? r0 : ((Pprev >> (2 * r0)) & 3);
            const int Pfull = __shfl(P, 63, 64);
            r0 = (Pfull >> (2 * r0)) & 3;   // carry to next group

            // ---- replay with true incoming state ----
            int s = sin0;
            float sp[4];
#pragma unroll
            for (int k = 0; k < 4; ++k) {
                const int spike = (s == 0) & cand[k];
                sp[k] = spike ? 1.0f : 0.0f;
                s = (s > 0) ? (s - 1) : (cand[k] ? 3 : 0);
            }
            o0.x = sp[0]; o0.y = sp[1]; o0.z = sp[2]; o0.w = sp[3];
        }

        __builtin_nontemporal_store(o0, (f4*)(Orow + tb));

        // ---- rotate register sets ----
#pragma unroll
        for (int j = 0; j < 4; ++j) { Pv[j] = Cv[j]; Cv[j] = Nv[j]; Nv[j] = Lv[j]; }
    }
}

extern "C" void kernel_launch(void* const* d_in, const int* in_sizes, int n_in,
                              void* d_out, int out_size, void* d_ws, size_t ws_size,
                              hipStream_t stream) {
    const float* I       = (const float*)d_in[0];
    const float* tau_m   = (const float*)d_in[1];
    const float* tau_s   = (const float*)d_in[2];
    const float* v_th    = (const float*)d_in[3];
    const float* v_reset = (const float*)d_in[4];
    float* out = (float*)d_out;

    srm_kernel<<<dim3(NROWS / WPB), dim3(256), 0, stream>>>(
        I, tau_m, tau_s, v_th, v_reset, out);
}

// Round 7
// 158.166 us; speedup vs baseline: 14.4345x; 1.2530x over previous
//
#include <hip/hip_runtime.h>

// SRM neuron: per-row 50-tap 'same' conv -> threshold -> refractory scan.
// B=4096 rows, T=16384. One wave per row, 4 timesteps/lane, 64 groups of 256.
// R7: replace per-group {49 ds_bpermute + 49 cndmask + 4 IEEE divides} with
//     {wave-private LDS window tile (15 ds_read_b128) + 1 v_cmp vs a
//      precomputed exact threshold}. Conv FMA order identical to R6
//      (validated absmax 0.0). R6 was VALU-issue bound (84.7% VALUBusy,
//      ~850 slots/group); this cuts static work to ~250 slots/group.

#define TLEN  16384
#define NROWS 4096
#define GRP   256     // elements per group (64 lanes x 4)
#define NGRP  64      // groups per row
#define KLEN  50
#define WPB   4       // waves (rows) per 256-thread block
#define TILEW 336     // padded tile stride (floats); 16B-aligned

typedef float f4 __attribute__((ext_vector_type(4)));

__device__ __forceinline__ float uniformf(float x) {
    return __int_as_float(__builtin_amdgcn_readfirstlane(__float_as_int(x)));
}

// compose: r[s] = then[first[s]]  (apply `first`, then `then`)
__device__ __forceinline__ int map_compose(int first, int then) {
    int r = 0;
#pragma unroll
    for (int s = 0; s < 4; ++s) {
        int a = (first >> (2 * s)) & 3;
        int b = (then >> (2 * a)) & 3;
        r |= b << (2 * s);
    }
    return r;
}

// Smallest float a such that (v_reset + a/100.0f) >= v_th, using the exact
// same fp32 ops as the per-element test. Both ops are monotone non-decreasing
// in a, so {a : pred(a)} = [a*, +inf) and cand == (acc >= a*) EXACTLY.
__device__ float solve_thresh(float v_reset, float v_th) {
    // order-preserving float<->uint key map (finite floats only)
    auto tokey = [](float f) {
        unsigned u = __float_as_uint(f);
        return (u & 0x80000000u) ? ~u : (u | 0x80000000u);
    };
    auto fromkey = [](unsigned k) {
        unsigned u = (k & 0x80000000u) ? (k & 0x7FFFFFFFu) : ~k;
        return __uint_as_float(u);
    };
    const float maxf = 3.402823466e38f;
    unsigned lo = tokey(-maxf), hi = tokey(maxf);
    if (!((v_reset + maxf / 100.0f) >= v_th))
        return __uint_as_float(0x7F800000u);  // pred never true -> +inf
    while (lo < hi) {
        unsigned mid = lo + ((hi - lo) >> 1);
        float a = fromkey(mid);
        if ((v_reset + a / 100.0f) >= v_th) hi = mid;
        else lo = mid + 1;
    }
    return fromkey(lo);
}

__global__ __launch_bounds__(256)
void srm_kernel(const float* __restrict__ I,
                const float* __restrict__ p_tau_m,
                const float* __restrict__ p_tau_s,
                const float* __restrict__ p_v_th,
                const float* __restrict__ p_v_reset,
                float* __restrict__ out)
{
    __shared__ __align__(16) float tile[WPB][2][TILEW];

    const int lane = threadIdx.x & 63;
    const int wid  = threadIdx.x >> 6;
    const int row  = blockIdx.x * WPB + wid;

    const float tau_m   = p_tau_m[0];
    const float tau_s   = p_tau_s[0];
    const float v_th    = p_v_th[0];
    const float v_reset = p_v_reset[0];

    // Taps pinned wave-uniform (SGPR file). Same arithmetic as R1-R6
    // (validated absmax 0.0).
    float ku[KLEN];
    float ksum = 0.0f;
#pragma unroll
    for (int t = 0; t < KLEN; ++t) {
        float ft = (float)t;
        float v = expf(-ft / tau_m) - expf(-ft / tau_s);
        ksum += v;
        ku[t] = uniformf(v);
    }
    const float kden = uniformf(ksum + 1e-10f);
    float kt[KLEN];
#pragma unroll
    for (int t = 0; t < KLEN; ++t) kt[t] = uniformf(ku[t] / kden);

    // Exact threshold: cand = (acc >= athr) <=> (v_reset + acc/100 >= v_th)
    const float athr = uniformf(solve_thresh(v_reset, v_th));

    const float* Irow = I + (size_t)row * TLEN;
    float* Orow = out + (size_t)row * TLEN;

    // Small rotating reg sets kept only for tile/halo writes.
    float Cv[4], Nv[4], Lv[4];
    {
        f4 a = *(const f4*)(Irow + 0 * GRP + 4 * lane);
        Cv[0] = a.x; Cv[1] = a.y; Cv[2] = a.z; Cv[3] = a.w;
        f4 c = *(const f4*)(Irow + 1 * GRP + 4 * lane);
        Nv[0] = c.x; Nv[1] = c.y; Nv[2] = c.z; Nv[3] = c.w;
    }

    // Prologue: tile0 halo-left = zeros (x[t<0]=0), tile0 main = group 0.
    if (lane < 8) {
        f4 z = (f4){0.0f, 0.0f, 0.0f, 0.0f};
        *(f4*)&tile[wid][0][4 * lane] = z;
    }
    {
        f4 c; c.x = Cv[0]; c.y = Cv[1]; c.z = Cv[2]; c.w = Cv[3];
        *(f4*)&tile[wid][0][32 + 4 * lane] = c;
    }

    int r0 = 0;  // wave-uniform refractory state entering this group

    for (int g = 0; g < NGRP; ++g) {
        const int cur = g & 1;
        const int nxt = cur ^ 1;

        // ---- prefetch group g+2 (zeros past end), streaming load ----
        if (g + 2 < NGRP) {
            f4 a = __builtin_nontemporal_load(
                (const f4*)(Irow + (size_t)(g + 2) * GRP + 4 * lane));
            Lv[0] = a.x; Lv[1] = a.y; Lv[2] = a.z; Lv[3] = a.w;
        } else {
            Lv[0] = Lv[1] = Lv[2] = Lv[3] = 0.0f;
        }

        // ---- tile maintenance (wave-private LDS; same-wave DS ops are
        //      in-order, no barrier needed) ----
        f4 nv; nv.x = Nv[0]; nv.y = Nv[1]; nv.z = Nv[2]; nv.w = Nv[3];
        if (lane < 8)
            *(f4*)&tile[wid][cur][288 + 4 * lane] = nv;  // cur halo-right = g+1 first 32
        *(f4*)&tile[wid][nxt][32 + 4 * lane] = nv;        // nxt main = group g+1
        if (lane >= 56) {
            f4 cv; cv.x = Cv[0]; cv.y = Cv[1]; cv.z = Cv[2]; cv.w = Cv[3];
            *(f4*)&tile[wid][nxt][4 * (lane - 56)] = cv;  // nxt halo-left = g last 32
        }

        // ---- window read: elems 4l+4 .. 4l+63 (time t0+4l-28 .. t0+4l+31) ----
        f4 wv[15];
#pragma unroll
        for (int i = 0; i < 15; ++i)
            wv[i] = *(const f4*)&tile[wid][cur][4 * lane + 4 + 4 * i];
#define WIN(m) (wv[(m) >> 2][(m) & 3])

        // ---- convolution: identical order/operands to R6 ----
        float acc[4];
        acc[0] = acc[1] = acc[2] = acc[3] = 0.0f;
#pragma unroll
        for (int o = -25; o <= 27; ++o) {
            const float w = WIN(o + 28);
#pragma unroll
            for (int k = 0; k < 4; ++k) {
                const int jj = k + 24 - o;
                if (jj >= 0 && jj < KLEN)
                    acc[k] = fmaf(kt[jj], w, acc[k]);
            }
        }
#undef WIN

        // ---- candidates: single compare vs exact threshold ----
        const int tb = g * GRP + 4 * lane;
        int cand[4];
#pragma unroll
        for (int k = 0; k < 4; ++k)
            cand[k] = (acc[k] >= athr) ? 1 : 0;
        cand[0] &= (tb != 0);   // spikes[0] forced 0 (loop starts at t=1)

        const int cm = cand[0] | cand[1] | cand[2] | cand[3];
        const unsigned long long anyc = __ballot(cm != 0);

        f4 o0;
        if (anyc == 0ULL) {
            // No crossing in this 256-group: all spikes zero; any refractory
            // countdown (<=3) expires within the group.
            o0 = (f4){0.0f, 0.0f, 0.0f, 0.0f};
            r0 = 0;
        } else {
            // ---- per-lane 4-step transfer map for incoming ref in {0..3} ----
            int s0 = 0, s1 = 1, s2 = 2, s3 = 3;
#pragma unroll
            for (int k = 0; k < 4; ++k) {
                const int c3 = cand[k] ? 3 : 0;
                s0 = (s0 > 0) ? (s0 - 1) : c3;
                s1 = (s1 > 0) ? (s1 - 1) : c3;
                s2 = (s2 > 0) ? (s2 - 1) : c3;
                s3 = (s3 > 0) ? (s3 - 1) : c3;
            }
            int P = s0 | (s1 << 2) | (s2 << 4) | (s3 << 6);

            // ---- inclusive prefix composition across 64 lanes ----
#pragma unroll
            for (int d = 1; d < 64; d <<= 1) {
                const int prev = __shfl_up(P, d, 64);
                const int comp = map_compose(prev, P);
                P = (lane >= d) ? comp : P;
            }
            const int Pprev = __shfl_up(P, 1, 64);
            const int sin0  = (lane == 0) ? r0 : ((Pprev >> (2 * r0)) & 3);
            const int Pfull = __shfl(P, 63, 64);
            r0 = (Pfull >> (2 * r0)) & 3;   // carry to next group

            // ---- replay with true incoming state ----
            int s = sin0;
            float sp[4];
#pragma unroll
            for (int k = 0; k < 4; ++k) {
                const int spike = (s == 0) & cand[k];
                sp[k] = spike ? 1.0f : 0.0f;
                s = (s > 0) ? (s - 1) : (cand[k] ? 3 : 0);
            }
            o0.x = sp[0]; o0.y = sp[1]; o0.z = sp[2]; o0.w = sp[3];
        }

        __builtin_nontemporal_store(o0, (f4*)(Orow + tb));

        // ---- rotate reg sets ----
#pragma unroll
        for (int j = 0; j < 4; ++j) { Cv[j] = Nv[j]; Nv[j] = Lv[j]; }
    }
}

extern "C" void kernel_launch(void* const* d_in, const int* in_sizes, int n_in,
                              void* d_out, int out_size, void* d_ws, size_t ws_size,
                              hipStream_t stream) {
    const float* I       = (const float*)d_in[0];
    const float* tau_m   = (const float*)d_in[1];
    const float* tau_s   = (const float*)d_in[2];
    const float* v_th    = (const float*)d_in[3];
    const float* v_reset = (const float*)d_in[4];
    float* out = (float*)d_out;

    srm_kernel<<<dim3(NROWS / WPB), dim3(256), 0, stream>>>(
        I, tau_m, tau_s, v_th, v_reset, out);
}